// Round 1
// baseline (144.685 us; speedup 1.0000x reference)
//
#include <hip/hip_runtime.h>

// Fused MLPKAN, round 6 restructure.
// Evidence: kan_fused absent from rocprof top-5 (all 40us fills) => kernel <40us.
// Cost model/CU: VALU ~7.5us floor, LDS ~12us (binding), L2 weight refetch ~8us.
// Changes vs round 5:
//  - x pre-transposed to xT[64][BATCH] in workspace (ws ~256MB per fill evidence);
//    layer0 reads x as wave-uniform broadcast float4 loads -> zero LDS for x.
//  - 8 waves = 8 i-groups of 8 (no bh split): ONE weight copy per block (was 2),
//    each wave owns all TB=32 batches in acc[32].
//  - h accumulated straight into ht[64][34] via ds_add_f32 (atomicAdd on LDS);
//    no hp partial buffer, no transpose pass. Layer1 partials via ds_add into
//    op[32][16]. LDS 59KB -> ~11KB per block.
// ht stride 34: v2f-aligned rows; ds_add writes 4-way bank-aliased (1.58x, ok);
// layer1 v2f reads conflict-free (4 distinct rows, bank offset 4 apart).

typedef float v2f __attribute__((ext_vector_type(2)));

#define BATCH 16384
#define TB    32

__global__ __launch_bounds__(256) void xpose64(const float* __restrict__ x,
                                               float* __restrict__ xT)
{
    __shared__ float tile[64][65];
    const int t = threadIdx.x;
    const long b0 = (long)blockIdx.x * 64;
#pragma unroll
    for (int p = 0; p < 4; ++p) {
        const int idx = (p * 256 + t) * 4;   // 0..4095
        const int b = idx >> 6;
        const int i = idx & 63;
        const float4 v = *(const float4*)(x + (b0 + b) * 64 + i);
        tile[i][b] = v.x; tile[i + 1][b] = v.y; tile[i + 2][b] = v.z; tile[i + 3][b] = v.w;
    }
    __syncthreads();
#pragma unroll
    for (int p = 0; p < 4; ++p) {
        const int idx = (p * 256 + t) * 4;
        const int i = idx >> 6;
        const int b = idx & 63;
        float4 v;
        v.x = tile[i][b]; v.y = tile[i][b + 1]; v.z = tile[i][b + 2]; v.w = tile[i][b + 3];
        *(float4*)(xT + (long)i * BATCH + b0 + b) = v;
    }
}

template<bool XT>
__global__ __launch_bounds__(512, 4) void kan_fused2(
    const float* __restrict__ x, const float* __restrict__ xT,
    const float* __restrict__ A1, const float* __restrict__ a1,
    const float* __restrict__ A2, const float* __restrict__ a2,
    const float* __restrict__ A3, const float* __restrict__ a3,
    const float* __restrict__ B1, const float* __restrict__ c1,
    const float* __restrict__ B2, const float* __restrict__ c2,
    const float* __restrict__ B3, const float* __restrict__ c3,
    float* __restrict__ out)
{
    __shared__ float ht[64][34];   // h transposed: ht[i1][b], ds_add accumulated
    __shared__ float op[TB][16];   // layer1 output accum

    const int t    = threadIdx.x;
    const int lane = t & 63;
    const int w    = t >> 6;       // 0..7 = i-group
    const int bB0  = blockIdx.x * TB;

    // zero LDS accumulators
    {
        float* hb = &ht[0][0];
        for (int k = t; k < 64 * 34; k += 512) hb[k] = 0.f;
        (&op[0][0])[t] = 0.f;      // TB*16 == 512
    }
    __syncthreads();

    const v2f zz = {0.f, 0.f};

    // ================= layer 0: 64 -> 64, wave = 8 i's, lane = o =================
    {
        const int o  = lane;
        const int i0 = 8 * w;

        auto ldw = [&](int i, v2f& w1, v2f& d1, float4& w2, v2f& d2, v2f& w3, float& b3v) {
            const int n = (i << 6) + o;
            w1  = *(const v2f*)(A1 + 2 * n);
            d1  = *(const v2f*)(a1 + 2 * n);
            w2  = *(const float4*)(A2 + 4 * n);
            d2  = *(const v2f*)(a2 + 2 * n);
            w3  = *(const v2f*)(A3 + 2 * n);
            b3v = a3[n];
        };

        float acc[TB];
#pragma unroll
        for (int j = 0; j < TB; ++j) acc[j] = 0.f;
        float bsum = 0.f;

        v2f w1, d1, d2, w3; float4 w2; float b3v;
        ldw(i0, w1, d1, w2, d2, w3, b3v);

#pragma unroll 1
        for (int ii = 0; ii < 8; ++ii) {
            const int i = i0 + ii;
            v2f nw1, nd1, nd2, nw3; float4 nw2; float nb3;
            ldw(i0 + ((ii + 1) & 7), nw1, nd1, nw2, nd2, nw3, nb3);  // in flight

            float4 xq[8];                       // 32 batch values, wave-uniform
            if constexpr (XT) {
                const float* xr = xT + (long)i * BATCH + bB0;
#pragma unroll
                for (int q = 0; q < 8; ++q) xq[q] = *(const float4*)(xr + 4 * q);
            } else {
#pragma unroll
                for (int q = 0; q < 8; ++q) {
                    float4 v;
                    v.x = x[(long)(bB0 + 4 * q + 0) * 64 + i];
                    v.y = x[(long)(bB0 + 4 * q + 1) * 64 + i];
                    v.z = x[(long)(bB0 + 4 * q + 2) * 64 + i];
                    v.w = x[(long)(bB0 + 4 * q + 3) * 64 + i];
                    xq[q] = v;
                }
            }

            bsum += b3v;
            const v2f c0  = {w2.x, w2.z};
            const v2f c1v = {w2.y, w2.w};
#pragma unroll
            for (int j = 0; j < TB; ++j) {
                const float xb = ((const float*)xq)[j];
                const v2f xd = {xb, xb};
                v2f m = __builtin_elementwise_fma(xd, w1, d1);
                m = __builtin_elementwise_max(m, zz);
                const v2f mm0 = {m.x, m.x};
                const v2f mm1 = {m.y, m.y};
                v2f tt = __builtin_elementwise_fma(c1v, mm1, d2);
                tt = __builtin_elementwise_fma(c0, mm0, tt);
                tt = __builtin_elementwise_max(tt, zz);
                acc[j] = fmaf(w3.x, tt.x, fmaf(w3.y, tt.y, acc[j]));
            }
            w1 = nw1; d1 = nd1; w2 = nw2; d2 = nd2; w3 = nw3; b3v = nb3;
        }

        // accumulate this wave's 8-i contribution; 4-way bank alias (free-ish)
#pragma unroll
        for (int j = 0; j < TB; ++j)
            atomicAdd(&ht[o][j], acc[j] + bsum);
    }
    __syncthreads();

    // ================= layer 1: 64 -> 16, lane = (ig, o1), wave = 8 i's =========
    {
        const int o1 = lane & 15;
        const int ig = lane >> 4;              // 4 groups x 2 i's

        float acc[TB];
#pragma unroll
        for (int j = 0; j < TB; ++j) acc[j] = 0.f;
        float bsum = 0.f;

#pragma unroll
        for (int ii = 0; ii < 2; ++ii) {
            const int i = 8 * w + 2 * ig + ii;
            const int n = (i << 4) + o1;
            const v2f w1    = *(const v2f*)(B1 + 2 * n);
            const v2f d1    = *(const v2f*)(c1 + 2 * n);
            const float4 w2 = *(const float4*)(B2 + 4 * n);
            const v2f d2    = *(const v2f*)(c2 + 2 * n);
            const v2f w3    = *(const v2f*)(B3 + 2 * n);
            bsum += c3[n];

            v2f hv[16];                        // ht row: 16 b64, conflict-free
#pragma unroll
            for (int q = 0; q < 16; ++q) hv[q] = *(const v2f*)(&ht[i][2 * q]);

            const v2f c0  = {w2.x, w2.z};
            const v2f c1v = {w2.y, w2.w};
#pragma unroll
            for (int j = 0; j < TB; ++j) {
                const float hb = ((const float*)hv)[j];
                const v2f xd = {hb, hb};
                v2f m = __builtin_elementwise_fma(xd, w1, d1);
                m = __builtin_elementwise_max(m, zz);
                const v2f mm0 = {m.x, m.x};
                const v2f mm1 = {m.y, m.y};
                v2f tt = __builtin_elementwise_fma(c1v, mm1, d2);
                tt = __builtin_elementwise_fma(c0, mm0, tt);
                tt = __builtin_elementwise_max(tt, zz);
                acc[j] = fmaf(w3.x, tt.x, fmaf(w3.y, tt.y, acc[j]));
            }
        }

        // reduce over ig within wave, then ds_add across waves
#pragma unroll
        for (int j = 0; j < TB; ++j) {
            float v = acc[j] + bsum;
            v += __shfl_xor(v, 16, 64);
            v += __shfl_xor(v, 32, 64);
            if (ig == 0) atomicAdd(&op[j][o1], v);
        }
    }
    __syncthreads();

    // ---- store: 512 floats, float4 coalesced ----
    if (t < 128) {
        const float4 r = *(const float4*)(&op[0][0] + t * 4);
        *(float4*)(out + (long)bB0 * 16 + t * 4) = r;
    }
}

extern "C" void kernel_launch(void* const* d_in, const int* in_sizes, int n_in,
                              void* d_out, int out_size, void* d_ws, size_t ws_size,
                              hipStream_t stream) {
    const float* x     = (const float*)d_in[0];
    const float* l0_W1 = (const float*)d_in[1];
    const float* l0_b1 = (const float*)d_in[2];
    const float* l0_W2 = (const float*)d_in[3];
    const float* l0_b2 = (const float*)d_in[4];
    const float* l0_W3 = (const float*)d_in[5];
    const float* l0_b3 = (const float*)d_in[6];
    const float* l1_W1 = (const float*)d_in[7];
    const float* l1_b1 = (const float*)d_in[8];
    const float* l1_W2 = (const float*)d_in[9];
    const float* l1_b2 = (const float*)d_in[10];
    const float* l1_W3 = (const float*)d_in[11];
    const float* l1_b3 = (const float*)d_in[12];

    float* outp = (float*)d_out;
    float* xT   = (float*)d_ws;
    const bool use_xt = (d_ws != nullptr) &&
                        (ws_size >= (size_t)BATCH * 64 * sizeof(float));

    dim3 blk(512);
    dim3 grid(BATCH / TB);   // 512 blocks, 2 per CU, 4 waves/SIMD

    if (use_xt) {
        hipLaunchKernelGGL(xpose64, dim3(BATCH / 64), dim3(256), 0, stream, x, xT);
        hipLaunchKernelGGL(kan_fused2<true>, grid, blk, 0, stream,
                           x, xT,
                           l0_W1, l0_b1, l0_W2, l0_b2, l0_W3, l0_b3,
                           l1_W1, l1_b1, l1_W2, l1_b2, l1_W3, l1_b3,
                           outp);
    } else {
        hipLaunchKernelGGL(kan_fused2<false>, grid, blk, 0, stream,
                           x, x,
                           l0_W1, l0_b1, l0_W2, l0_b2, l0_W3, l0_b3,
                           l1_W1, l1_b1, l1_W2, l1_b2, l1_W3, l1_b3,
                           outp);
    }
}